// Round 1
// baseline (703.151 us; speedup 1.0000x reference)
//
#include <hip/hip_runtime.h>
#include <hip/hip_bf16.h>

#define N_BINS 15
#define C_DIM 64

// d_ws layout: [0..14] sum_conf, [15..29] sum_acc, [30..44] count  (floats)

__global__ void ece_main(const float* __restrict__ probs,
                         const int* __restrict__ labels,
                         float* __restrict__ gbins, int N) {
    __shared__ float s_conf[N_BINS];
    __shared__ float s_acc[N_BINS];
    __shared__ float s_cnt[N_BINS];

    const int tid = threadIdx.x;
    if (tid < N_BINS) { s_conf[tid] = 0.f; s_acc[tid] = 0.f; s_cnt[tid] = 0.f; }
    __syncthreads();

    const int lane = tid & 63;
    const int wave = tid >> 6;                // wave index within block
    const int sub  = lane >> 4;               // which of the 4 rows this lane helps with
    const int l16  = lane & 15;               // position within row (x4 floats)
    const int wavesPerBlock = blockDim.x >> 6;

    long long g      = (long long)blockIdx.x * wavesPerBlock + wave;  // group of 4 rows
    const long long gstride = (long long)gridDim.x * wavesPerBlock;

    for (; g * 4 < (long long)N; g += gstride) {
        const long long row = g * 4 + sub;
        const bool rowvalid = row < (long long)N;

        float conf; int pred;
        if (rowvalid) {
            const float4 v = *(const float4*)(probs + row * C_DIM + l16 * 4);
            float m = v.x; int a = l16 * 4;
            if (v.y > m) { m = v.y; a = l16 * 4 + 1; }
            if (v.z > m) { m = v.z; a = l16 * 4 + 2; }
            if (v.w > m) { m = v.w; a = l16 * 4 + 3; }
            conf = m; pred = a;
        } else {
            conf = -1.f; pred = 0;
        }

        // reduce (max, first-argmax) across the 16-lane subgroup
        #pragma unroll
        for (int off = 1; off < 16; off <<= 1) {
            float om = __shfl_xor(conf, off, 64);
            int   oa = __shfl_xor(pred, off, 64);
            if (om > conf || (om == conf && oa < pred)) { conf = om; pred = oa; }
        }

        if (l16 == 0 && rowvalid) {
            const int lab = labels[row];
            const float acc = (pred == lab) ? 1.f : 0.f;
            if (conf > 0.f) {
                int bin = (int)ceilf(conf * 15.f) - 1;
                bin = min(max(bin, 0), N_BINS - 1);
                atomicAdd(&s_conf[bin], conf);
                atomicAdd(&s_acc[bin], acc);
                atomicAdd(&s_cnt[bin], 1.f);
            }
        }
    }

    __syncthreads();
    if (tid < N_BINS) {
        atomicAdd(&gbins[tid],              s_conf[tid]);
        atomicAdd(&gbins[N_BINS + tid],     s_acc[tid]);
        atomicAdd(&gbins[2 * N_BINS + tid], s_cnt[tid]);
    }
}

__global__ void ece_final(const float* __restrict__ gbins,
                          float* __restrict__ out, int N) {
    if (threadIdx.x == 0 && blockIdx.x == 0) {
        float ece = 0.f;
        const float invN = 1.f / (float)N;
        for (int b = 0; b < N_BINS; b++) {
            const float sc = gbins[b];
            const float sa = gbins[N_BINS + b];
            const float cn = gbins[2 * N_BINS + b];
            if (cn > 0.f) {
                const float avg_conf = sc / cn;
                const float avg_acc  = sa / cn;
                ece += fabsf(avg_conf - avg_acc) * (cn * invN);
            }
        }
        out[0] = ece;
    }
}

extern "C" void kernel_launch(void* const* d_in, const int* in_sizes, int n_in,
                              void* d_out, int out_size, void* d_ws, size_t ws_size,
                              hipStream_t stream) {
    const float* probs  = (const float*)d_in[0];
    const int*   labels = (const int*)d_in[1];
    float* gbins = (float*)d_ws;
    float* out   = (float*)d_out;

    const int N = in_sizes[1];   // number of rows (labels count)

    // zero the 45-float accumulator workspace (graph-capture safe)
    hipMemsetAsync(d_ws, 0, 3 * N_BINS * sizeof(float), stream);

    const int threads = 256;           // 4 waves/block
    const int blocks  = 2048;          // grid-stride; ~32 waves/CU
    ece_main<<<blocks, threads, 0, stream>>>(probs, labels, gbins, N);
    ece_final<<<1, 64, 0, stream>>>(gbins, out, N);
}

// Round 2
// 667.028 us; speedup vs baseline: 1.0542x; 1.0542x over previous
//
#include <hip/hip_runtime.h>
#include <hip/hip_bf16.h>

#define N_BINS 15
#define C_DIM 64

// d_ws layout: [0..14] sum_conf, [15..29] sum_acc, [30..44] count  (floats)

__global__ __launch_bounds__(256) void ece_main(const float* __restrict__ probs,
                                                const int* __restrict__ labels,
                                                float* __restrict__ gbins, int N) {
    __shared__ float s_bins[3 * N_BINS];
    const int tid = threadIdx.x;
    if (tid < 3 * N_BINS) s_bins[tid] = 0.f;
    __syncthreads();

    // private accumulators for the two hottest bins (conf = max of 64 U(0,1)
    // lands in bin 14 ~98.8% of the time, bin 13 ~1.2%)
    float c14 = 0.f, a14 = 0.f, n14 = 0.f;
    float c13 = 0.f, a13 = 0.f, n13 = 0.f;

    const int stride = gridDim.x * blockDim.x;
    for (int row = blockIdx.x * blockDim.x + tid; row < N; row += stride) {
        const int lab = labels[row];
        const float4* p4 = (const float4*)(probs + (size_t)row * C_DIM);

        float4 v[16];
        #pragma unroll
        for (int j = 0; j < 16; j++) v[j] = p4[j];   // 16 independent dwordx4 loads

        // first-occurrence argmax over 64 elements, fully in-thread
        float best = v[0].x; int idx = 0;
        #pragma unroll
        for (int j = 0; j < 16; j++) {
            if (v[j].x > best) { best = v[j].x; idx = 4 * j + 0; }
            if (v[j].y > best) { best = v[j].y; idx = 4 * j + 1; }
            if (v[j].z > best) { best = v[j].z; idx = 4 * j + 2; }
            if (v[j].w > best) { best = v[j].w; idx = 4 * j + 3; }
        }

        const float conf = best;
        const float acc = (idx == lab) ? 1.f : 0.f;
        if (conf > 0.f) {
            int bin = (int)ceilf(conf * 15.f) - 1;           // (lower, upper] bins
            bin = min(max(bin, 0), N_BINS - 1);
            if (bin == 14)      { c14 += conf; a14 += acc; n14 += 1.f; }
            else if (bin == 13) { c13 += conf; a13 += acc; n13 += 1.f; }
            else {                                            // ~1e-4 of rows
                atomicAdd(&s_bins[bin],             conf);
                atomicAdd(&s_bins[N_BINS + bin],    acc);
                atomicAdd(&s_bins[2 * N_BINS + bin], 1.f);
            }
        }
    }

    // wave-level butterfly reduce of the 6 private accumulators
    #pragma unroll
    for (int off = 32; off > 0; off >>= 1) {
        c14 += __shfl_xor(c14, off, 64);
        a14 += __shfl_xor(a14, off, 64);
        n14 += __shfl_xor(n14, off, 64);
        c13 += __shfl_xor(c13, off, 64);
        a13 += __shfl_xor(a13, off, 64);
        n13 += __shfl_xor(n13, off, 64);
    }
    if ((tid & 63) == 0) {
        atomicAdd(&s_bins[14],              c14);
        atomicAdd(&s_bins[N_BINS + 14],     a14);
        atomicAdd(&s_bins[2 * N_BINS + 14], n14);
        atomicAdd(&s_bins[13],              c13);
        atomicAdd(&s_bins[N_BINS + 13],     a13);
        atomicAdd(&s_bins[2 * N_BINS + 13], n13);
    }
    __syncthreads();
    if (tid < 3 * N_BINS) atomicAdd(&gbins[tid], s_bins[tid]);
}

__global__ void ece_final(const float* __restrict__ gbins,
                          float* __restrict__ out, int N) {
    if (threadIdx.x == 0 && blockIdx.x == 0) {
        float ece = 0.f;
        const float invN = 1.f / (float)N;
        for (int b = 0; b < N_BINS; b++) {
            const float sc = gbins[b];
            const float sa = gbins[N_BINS + b];
            const float cn = gbins[2 * N_BINS + b];
            if (cn > 0.f) {
                const float avg_conf = sc / cn;
                const float avg_acc  = sa / cn;
                ece += fabsf(avg_conf - avg_acc) * (cn * invN);
            }
        }
        out[0] = ece;
    }
}

extern "C" void kernel_launch(void* const* d_in, const int* in_sizes, int n_in,
                              void* d_out, int out_size, void* d_ws, size_t ws_size,
                              hipStream_t stream) {
    const float* probs  = (const float*)d_in[0];
    const int*   labels = (const int*)d_in[1];
    float* gbins = (float*)d_ws;
    float* out   = (float*)d_out;

    const int N = in_sizes[1];   // number of rows (labels count)

    hipMemsetAsync(d_ws, 0, 3 * N_BINS * sizeof(float), stream);

    const int threads = 256;
    const int blocks  = 2048;    // ~524K threads, ~4 rows/thread grid-stride
    ece_main<<<blocks, threads, 0, stream>>>(probs, labels, gbins, N);
    ece_final<<<1, 64, 0, stream>>>(gbins, out, N);
}

// Round 3
// 662.585 us; speedup vs baseline: 1.0612x; 1.0067x over previous
//
#include <hip/hip_runtime.h>
#include <hip/hip_bf16.h>

#define N_BINS 15
#define C_DIM 64

// d_ws layout: [0..14] sum_conf, [15..29] sum_acc, [30..44] count  (floats)

__global__ __launch_bounds__(256) void ece_main(const float* __restrict__ probs,
                                                const int* __restrict__ labels,
                                                float* __restrict__ gbins, int N) {
    __shared__ float s_bins[3 * N_BINS];
    const int tid = threadIdx.x;
    if (tid < 3 * N_BINS) s_bins[tid] = 0.f;
    __syncthreads();

    const int lane = tid & 63;
    const int wave = tid >> 6;
    const int sub  = lane >> 4;   // which of the group's 4 rows this lane helps
    const int l16  = lane & 15;   // position within the row (float4 granularity)
    const int wavesPerBlock = blockDim.x >> 6;

    // private accumulators (bin14 ~98.8% of rows, bin13 ~1.2%)
    float c14 = 0.f, a14 = 0.f, n14 = 0.f;
    float c13 = 0.f, a13 = 0.f, n13 = 0.f;

    const long long nGroups = ((long long)N + 3) >> 2;          // groups of 4 rows
    long long g0 = ((long long)blockIdx.x * wavesPerBlock + wave) * 4;
    const long long gstride = (long long)gridDim.x * wavesPerBlock * 4;

    for (; g0 < nGroups; g0 += gstride) {
        float4 v[4];
        int lab[4];
        bool rv[4];

        const bool fullIter = (g0 * 4 + 16) <= (long long)N;    // all 16 rows valid
        if (fullIter) {
            #pragma unroll
            for (int gi = 0; gi < 4; gi++) {
                const long long grp = g0 + gi;
                // one contiguous 1 KB wave-load: lane L covers bytes L*16..L*16+15
                v[gi] = *(const float4*)(probs + grp * 256 + lane * 4);
                rv[gi] = true;
                if (l16 == 0) lab[gi] = labels[grp * 4 + sub];
            }
        } else {
            #pragma unroll
            for (int gi = 0; gi < 4; gi++) {
                const long long grp = g0 + gi;
                const long long row = grp * 4 + sub;
                rv[gi] = (grp < nGroups) && (row < (long long)N);
                if (rv[gi]) {
                    v[gi] = *(const float4*)(probs + grp * 256 + lane * 4);
                    if (l16 == 0) lab[gi] = labels[row];
                } else {
                    v[gi] = make_float4(-1.f, -1.f, -1.f, -1.f);
                }
            }
        }

        #pragma unroll
        for (int gi = 0; gi < 4; gi++) {
            // local first-occurrence argmax over this lane's 4 elements
            float conf; int pred;
            {
                const float4 x = v[gi];
                float m = x.x; int a = l16 * 4;
                if (x.y > m) { m = x.y; a = l16 * 4 + 1; }
                if (x.z > m) { m = x.z; a = l16 * 4 + 2; }
                if (x.w > m) { m = x.w; a = l16 * 4 + 3; }
                conf = rv[gi] ? m : -1.f;
                pred = a;
            }
            // reduce (max, first-argmax) across the 16-lane subgroup
            #pragma unroll
            for (int off = 1; off < 16; off <<= 1) {
                const float om = __shfl_xor(conf, off, 64);
                const int   oa = __shfl_xor(pred, off, 64);
                if (om > conf || (om == conf && oa < pred)) { conf = om; pred = oa; }
            }
            if (l16 == 0 && rv[gi] && conf > 0.f) {
                const float acc = (pred == lab[gi]) ? 1.f : 0.f;
                int bin = (int)ceilf(conf * 15.f) - 1;          // (lower, upper] bins
                bin = min(max(bin, 0), N_BINS - 1);
                if (bin == 14)      { c14 += conf; a14 += acc; n14 += 1.f; }
                else if (bin == 13) { c13 += conf; a13 += acc; n13 += 1.f; }
                else {                                           // ~1e-4 of rows
                    atomicAdd(&s_bins[bin],              conf);
                    atomicAdd(&s_bins[N_BINS + bin],     acc);
                    atomicAdd(&s_bins[2 * N_BINS + bin], 1.f);
                }
            }
        }
    }

    // privates are nonzero only on lanes 0/16/32/48 → 2-step reduce to lane 0
    #pragma unroll
    for (int off = 16; off <= 32; off <<= 1) {
        c14 += __shfl_xor(c14, off, 64);
        a14 += __shfl_xor(a14, off, 64);
        n14 += __shfl_xor(n14, off, 64);
        c13 += __shfl_xor(c13, off, 64);
        a13 += __shfl_xor(a13, off, 64);
        n13 += __shfl_xor(n13, off, 64);
    }
    if (lane == 0) {
        atomicAdd(&s_bins[14],              c14);
        atomicAdd(&s_bins[N_BINS + 14],     a14);
        atomicAdd(&s_bins[2 * N_BINS + 14], n14);
        atomicAdd(&s_bins[13],              c13);
        atomicAdd(&s_bins[N_BINS + 13],     a13);
        atomicAdd(&s_bins[2 * N_BINS + 13], n13);
    }
    __syncthreads();
    // flush only nonzero bins → ~6 instead of 45 global atomics per block
    if (tid < 3 * N_BINS && s_bins[tid] != 0.f) atomicAdd(&gbins[tid], s_bins[tid]);
}

__global__ void ece_final(const float* __restrict__ gbins,
                          float* __restrict__ out, int N) {
    if (threadIdx.x == 0 && blockIdx.x == 0) {
        float ece = 0.f;
        const float invN = 1.f / (float)N;
        for (int b = 0; b < N_BINS; b++) {
            const float sc = gbins[b];
            const float sa = gbins[N_BINS + b];
            const float cn = gbins[2 * N_BINS + b];
            if (cn > 0.f) {
                const float avg_conf = sc / cn;
                const float avg_acc  = sa / cn;
                ece += fabsf(avg_conf - avg_acc) * (cn * invN);
            }
        }
        out[0] = ece;
    }
}

extern "C" void kernel_launch(void* const* d_in, const int* in_sizes, int n_in,
                              void* d_out, int out_size, void* d_ws, size_t ws_size,
                              hipStream_t stream) {
    const float* probs  = (const float*)d_in[0];
    const int*   labels = (const int*)d_in[1];
    float* gbins = (float*)d_ws;
    float* out   = (float*)d_out;

    const int N = in_sizes[1];   // number of rows (labels count)

    hipMemsetAsync(d_ws, 0, 3 * N_BINS * sizeof(float), stream);

    const int threads = 256;     // 4 waves/block
    const int blocks  = 2048;    // 8192 waves = 32 waves/CU
    ece_main<<<blocks, threads, 0, stream>>>(probs, labels, gbins, N);
    ece_final<<<1, 64, 0, stream>>>(gbins, out, N);
}